// Round 3
// baseline (504.605 us; speedup 1.0000x reference)
//
#include <hip/hip_runtime.h>
#include <cstdint>
#include <cstddef>

// ---------------- constants ----------------
#define BATCH 8
#define NPTS 2048
#define KNN 20
#define M1 327680   // BATCH*NPTS*KNN
#define M2 16384    // BATCH*NPTS

typedef unsigned short ushort_t;
typedef unsigned long long u64;
typedef __attribute__((ext_vector_type(8))) short bf16x8;   // 8 bf16 = 4 VGPRs
typedef __attribute__((ext_vector_type(4))) float f32x4;    // MFMA acc
typedef __attribute__((ext_vector_type(2))) int int2v;

// ws layout (bytes) — total 181,121,024
// xt is float4 {x,y,z,xx}: 16384*16 = 262144 B.
#define OFF_XT    0UL          // 262144   float4 xt4[b*n]
#define OFF_IDX   262144UL     // 1310720  int idx[b*n][20]
#define OFF_WH2   1572864UL    // 8192   bf16 [64][64]
#define OFF_WH3   1589248UL    // 16384  bf16 [128][64]
#define OFF_WH4   1622016UL    // 65536  bf16 [256][128]
#define OFF_WH5   1753088UL    // 524288 bf16 [512][512]
#define OFF_SS    2842624UL    // 20480   5 x (512 scale + 512 shift) float
// REG0: y1 [M1][64] (41.9MB) -> y3 [M1][128] (83.9MB) -> y5 [M2][512] (16.8MB)
#define OFF_REG0  2863104UL    // 83886080
// REG1: y2 [M1][64] (41.9MB)
#define OFF_REG1  86749184UL   // 41943040
#define OFF_XCAT  128692224UL  // 16777216 xcat[M2][512] bf16
#define OFF_RAWMAX 145469440UL // 16777216 f32 [16384][<=256]
#define OFF_RAWMIN 162246656UL // 16777216
#define OFF_SP     179023872UL // 2097152  f32 partials
#define WS_NEEDED  181121024UL

// ---------------- helpers ----------------
__device__ __forceinline__ float bf2f(unsigned short u) {
    union { unsigned int i; float f; } c; c.i = ((unsigned int)u) << 16; return c.f;
}
__device__ __forceinline__ unsigned short f2bf(float f) {
    union { float f; unsigned int i; } c; c.f = f;
    unsigned int x = c.i;
    unsigned int r = (x + 0x7fffu + ((x >> 16) & 1u)) >> 16;  // RNE
    return (unsigned short)r;
}
__device__ __forceinline__ unsigned int pack2(float a, float b) {
    return (unsigned int)f2bf(a) | ((unsigned int)f2bf(b) << 16);
}
__device__ __forceinline__ void unpack8(uint4 u, float* v) {
    v[0] = bf2f((unsigned short)(u.x & 0xffffu)); v[1] = bf2f((unsigned short)(u.x >> 16));
    v[2] = bf2f((unsigned short)(u.y & 0xffffu)); v[3] = bf2f((unsigned short)(u.y >> 16));
    v[4] = bf2f((unsigned short)(u.z & 0xffffu)); v[5] = bf2f((unsigned short)(u.z >> 16));
    v[6] = bf2f((unsigned short)(u.w & 0xffffu)); v[7] = bf2f((unsigned short)(u.w >> 16));
}

// ---------------- prep: transpose x, compute xx, pack as float4 ----------------
__global__ void prep_k(const float* __restrict__ x, float4* __restrict__ xt4) {
    int t = blockIdx.x * 256 + threadIdx.x;   // 16384
    int b = t >> 11, n = t & 2047;
    float v0 = x[((size_t)b * 3 + 0) * NPTS + n];
    float v1 = x[((size_t)b * 3 + 1) * NPTS + n];
    float v2 = x[((size_t)b * 3 + 2) * NPTS + n];
    float xxv = __fadd_rn(__fadd_rn(__fmul_rn(v0, v0), __fmul_rn(v1, v1)), __fmul_rn(v2, v2));
    xt4[t] = make_float4(v0, v1, v2, xxv);
}

// ---------------- weight prep: single bf16 for all MFMA layers ----------------
__global__ void wsplit_all_k(const float* __restrict__ w2, ushort_t* __restrict__ wh2,
                             const float* __restrict__ w3, ushort_t* __restrict__ wh3,
                             const float* __restrict__ w4, ushort_t* __restrict__ wh4,
                             const float* __restrict__ w5, ushort_t* __restrict__ wh5) {
    int t = blockIdx.x * 256 + threadIdx.x;   // 307200 total
    if (t < 4096)        { wh2[t] = f2bf(w2[t]); }
    else if (t < 12288)  { int o = t - 4096;  wh3[o] = f2bf(w3[o]); }
    else if (t < 45056)  { int o = t - 12288; wh4[o] = f2bf(w4[o]); }
    else                 { int o = t - 45056; wh5[o] = f2bf(w5[o]); }
}

// ---------------- knn: 1 point per HALF-wave, f64 sortable keys ----------------
// r14: __shfl_xor butterfly -> DS saturation; DPP row_ror (VALU only).
// r15: u64 sortable keys -> single cmp_u64 merges.
// r16: permlane swaps all-reduce, myj accumulator, float4 xt, unroll 1.
// r17 (this round): (a) point-per-half-wave: 64 cand/lane (j = lane31 + 32q),
//   8 groups of 8; A and B reduce in ONE instruction stream: 4 ror + 1
//   permlane16_swap = 5 stage-executions/round (was 12). (b) keys as positive
//   f64: key = (1<<62)|(okey<<30)|(2047-j) -> every merge is one v_max_f64
//   (bit62 forces normal exponent: never denorm/NaN; sign=0 -> f64 order ==
//   integer order == (value desc, j asc), bit-identical tie-break to r16).
//   (c) rescan: two serialized per-half uniform 8-way switches.

__device__ __forceinline__ double mkkey(float m, unsigned idx11) {
    int u = __float_as_int(m);
    unsigned ok = (unsigned)(u ^ ((u >> 31) | 0x80000000));
    u64 k = (1ull << 62) | ((u64)ok << 30) | (u64)idx11;
    return __longlong_as_double((long long)k);
}

#define DPP_ROR(x, n) __builtin_amdgcn_update_dpp(0, (x), 0x120 + (n), 0xf, 0xf, true)

template<int N>
__device__ __forceinline__ void ror_max(double &k) {
    u64 u = (u64)__double_as_longlong(k);
    unsigned h  = (unsigned)DPP_ROR((int)(unsigned)(u >> 32), N);
    unsigned lo = (unsigned)DPP_ROR((int)(unsigned)u, N);
    double o = __longlong_as_double((long long)(((u64)h << 32) | lo));
    k = fmax(k, o);
}

// merge lane i with lane i^16 (rows 0<->1 within each half). VALU pipe, no DS.
__device__ __forceinline__ void swap16_max(double &k) {
    u64 u = (u64)__double_as_longlong(k);
    int2v ph = __builtin_amdgcn_permlane16_swap((int)(unsigned)(u >> 32), (int)(unsigned)(u >> 32), false, false);
    int2v pl = __builtin_amdgcn_permlane16_swap((int)(unsigned)u, (int)(unsigned)u, false, false);
    double a = __longlong_as_double((long long)(((u64)(unsigned)ph.x << 32) | (unsigned)pl.x));
    double b = __longlong_as_double((long long)(((u64)(unsigned)ph.y << 32) | (unsigned)pl.y));
    k = fmax(a, b);
}

template<int G>
__device__ __forceinline__ void knn_rescan8(float (&v)[64], double (&gk)[8],
                                            bool own, int qw, int lane31) {
#pragma unroll
    for (int q = G * 8; q < G * 8 + 8; q++)
        if (own && q == qw) v[q] = -3.4e38f;
    float m = v[G * 8]; int qi = G * 8;
#pragma unroll
    for (int q = G * 8 + 1; q < G * 8 + 8; q++)
        if (v[q] > m) { m = v[q]; qi = q; }
    gk[G] = mkkey(m, 2047u - (unsigned)(lane31 + (qi << 5)));
}

__device__ __forceinline__ void knn_rescan_any8(float (&v)[64], double (&gk)[8],
                                                int j, int lane31) {
    int qw = j >> 5;                 // candidate slot q in [0,64)
    bool own = (lane31 == (j & 31));
    switch (qw >> 3) {
        case 0: knn_rescan8<0>(v, gk, own, qw, lane31); break;
        case 1: knn_rescan8<1>(v, gk, own, qw, lane31); break;
        case 2: knn_rescan8<2>(v, gk, own, qw, lane31); break;
        case 3: knn_rescan8<3>(v, gk, own, qw, lane31); break;
        case 4: knn_rescan8<4>(v, gk, own, qw, lane31); break;
        case 5: knn_rescan8<5>(v, gk, own, qw, lane31); break;
        case 6: knn_rescan8<6>(v, gk, own, qw, lane31); break;
        default: knn_rescan8<7>(v, gk, own, qw, lane31); break;
    }
}

__launch_bounds__(256)
__global__ void knn_k(const float4* __restrict__ xt4, int* __restrict__ idx) {
    int tid = threadIdx.x;
    int l = tid & 63, wv = tid >> 6;
    int lane31 = l & 31, half = l >> 5;
    int basePid = blockIdx.x * 8 + wv * 2;
    int pid = basePid + half;                 // both halves in same batch
    int b = pid >> 11;
    const float4* xb4 = xt4 + (size_t)b * NPTS;
    float4 P = xb4[pid & 2047];
    float v[64];
#pragma unroll
    for (int q = 0; q < 64; q++) {
        float4 p = xb4[lane31 + q * 32];
        float d = __fadd_rn(__fadd_rn(__fmul_rn(P.x, p.x), __fmul_rn(P.y, p.y)), __fmul_rn(P.z, p.z));
        v[q] = __fsub_rn(__fsub_rn(-P.w, __fmul_rn(-2.0f, d)), p.w);
    }
    double gk[8];
#pragma unroll
    for (int g = 0; g < 8; g++) {
        float m = v[g * 8]; int qi = g * 8;
#pragma unroll
        for (int q = g * 8 + 1; q < g * 8 + 8; q++)
            if (v[q] > m) { m = v[q]; qi = q; }
        gk[g] = mkkey(m, 2047u - (unsigned)(lane31 + (qi << 5)));
    }
    unsigned myj = 0;
#pragma unroll 1
    for (int t = 0; t < KNN; t++) {
        double k = fmax(fmax(fmax(gk[0], gk[1]), fmax(gk[2], gk[3])),
                        fmax(fmax(gk[4], gk[5]), fmax(gk[6], gk[7])));
        ror_max<1>(k); ror_max<2>(k); ror_max<4>(k); ror_max<8>(k);
        swap16_max(k);
        // all lanes of each half now hold that half's winner key
        unsigned lo = (unsigned)(u64)__double_as_longlong(k);
        unsigned jv = 2047u - (lo & 2047u);
        myj = (l == t) ? jv : myj;
        myj = (l == t + 32) ? jv : myj;
        if (t == KNN - 1) break;
        int loA = __builtin_amdgcn_readlane((int)lo, 0);
        int loB = __builtin_amdgcn_readlane((int)lo, 32);
        int jA = 2047 - (loA & 2047);
        int jB = 2047 - (loB & 2047);
        if (l < 32) knn_rescan_any8(v, gk, jA, lane31);
        else        knn_rescan_any8(v, gk, jB, lane31);
    }
    if (l < KNN) idx[(size_t)basePid * KNN + l] = (int)myj;
    else if (l >= 32 && l < 32 + KNN) idx[(size_t)(basePid + 1) * KNN + (l - 32)] = (int)myj;
}

// ---------------- conv1 fused MFMA: graph-feature stager (K=32 zero-padded) + conv_fused
// epilogue (raw max/min per k-window + fp32 stats partials + y1 write). BO=64.
__launch_bounds__(256, 2)
__global__ void conv1_fused_k(const float4* __restrict__ xt4, const int* __restrict__ idx,
                              const float* __restrict__ w1, ushort_t* __restrict__ y1,
                              float* __restrict__ rawmax, float* __restrict__ rawmin,
                              float* __restrict__ sp) {
    __shared__ ushort_t hA[320 * 56];           // wreg overlays this in epilogue
    __shared__ ushort_t wHs[64 * 56];
    __shared__ float sw[4 * 64 * 2];
    const int tid = threadIdx.x;
    const int m0 = blockIdx.x * 320;            // 1024 m-tiles
    for (int i = tid; i < 512; i += 256) sw[i] = 0.0f;
    {
        int row = tid >> 2, seg = tid & 3;
        uint4 u = make_uint4(0, 0, 0, 0);
        if (seg == 0) {
            const float* wr = w1 + row * 6;
            u.x = pack2(wr[0], wr[1]);
            u.y = pack2(wr[2], wr[3]);
            u.z = pack2(wr[4], wr[5]);
        }
        *(uint4*)&wHs[row * 56 + seg * 8] = u;
    }
    for (int r = tid; r < 320; r += 256) {
        int m = m0 + r;
        int nb = m / KNN;
        int b = nb >> 11;
        int j = idx[m];
        float4 PI = xt4[nb];
        float4 PJ = xt4[(size_t)(b * NPTS + j)];
        uint4 u;
        u.x = pack2(PJ.x - PI.x, PJ.y - PI.y);
        u.y = pack2(PJ.z - PI.z, PI.x);
        u.z = pack2(PI.y, PI.z);
        u.w = 0;
        uint4 z = make_uint4(0, 0, 0, 0);
        *(uint4*)&hA[r * 56 + 0]  = u;
        *(uint4*)&hA[r * 56 + 8]  = z;
        *(uint4*)&hA[r * 56 + 16] = z;
        *(uint4*)&hA[r * 56 + 24] = z;
    }
    __syncthreads();
    const int lane = tid & 63, wv = tid >> 6;
    const int l15 = lane & 15, quad = lane >> 4;
    f32x4 acc[5][4];
#pragma unroll
    for (int mt = 0; mt < 5; mt++)
#pragma unroll
        for (int ot = 0; ot < 4; ot++) acc[mt][ot] = (f32x4){0.f, 0.f, 0.f, 0.f};
    bf16x8 a[5];
#pragma unroll
    for (int mt = 0; mt < 5; mt++)
        a[mt] = *(bf16x8*)&hA[(wv * 80 + mt * 16 + l15) * 56 + quad * 8];
#pragma unroll
    for (int ot = 0; ot < 4; ot++) {
        bf16x8 bh = *(bf16x8*)&wHs[(ot * 16 + l15) * 56 + quad * 8];
#pragma unroll
        for (int mt = 0; mt < 5; mt++)
            acc[mt][ot] = __builtin_amdgcn_mfma_f32_16x16x32_bf16(a[mt], bh, acc[mt][ot], 0, 0, 0);
    }
    __syncthreads();   // wreg overlays hA
    float* wreg = (float*)((char*)hA + wv * 6400);   // [80][20]
#pragma unroll
    for (int ot = 0; ot < 4; ot++) {
#pragma unroll
        for (int mt = 0; mt < 5; mt++)
#pragma unroll
            for (int r = 0; r < 4; r++)
                wreg[(mt * 16 + quad * 4 + r) * 20 + l15] = acc[mt][ot][r];
        __syncthreads();   // cross-lane round-trip (r7 lesson)
        {
            int pp = quad;
            const float* rr = wreg + (pp * 20) * 20 + l15;
            float mx = rr[0], mn = rr[0], sm = 0.0f, ss = 0.0f;
#pragma unroll
            for (int q = 0; q < 20; q++) {
                float vv = rr[q * 20];
                mx = fmaxf(mx, vv); mn = fminf(mn, vv);
                sm += vv; ss = fmaf(vv, vv, ss);
            }
            int pt = blockIdx.x * 16 + wv * 4 + pp;
            int o = ot * 16 + l15;
            rawmax[(size_t)pt * 64 + o] = mx;
            rawmin[(size_t)pt * 64 + o] = mn;
            sm += __shfl_xor(sm, 16); sm += __shfl_xor(sm, 32);
            ss += __shfl_xor(ss, 16); ss += __shfl_xor(ss, 32);
            if (lane < 16) {
                sw[(wv * 64 + ot * 16 + l15) * 2 + 0] += sm;
                sw[(wv * 64 + ot * 16 + l15) * 2 + 1] += ss;
            }
        }
#pragma unroll
        for (int it = 0; it < 3; it++) {
            int t = lane + it * 64;
            if (t < 160) {
                int row = t >> 1, half = t & 1;
                float4 f0 = *(float4*)&wreg[row * 20 + half * 8];
                float4 f1 = *(float4*)&wreg[row * 20 + half * 8 + 4];
                uint4 u;
                u.x = pack2(f0.x, f0.y); u.y = pack2(f0.z, f0.w);
                u.z = pack2(f1.x, f1.y); u.w = pack2(f1.z, f1.w);
                *(uint4*)(y1 + (size_t)(m0 + wv * 80 + row) * 64 + ot * 16 + half * 8) = u;
            }
        }
        __syncthreads();
    }
    if (tid < 128) {
        int ol = tid >> 1, st = tid & 1;
        float v = 0.0f;
#pragma unroll
        for (int w2 = 0; w2 < 4; w2++) v += sw[(w2 * 64 + ol) * 2 + st];
        sp[(size_t)blockIdx.x * 128 + ol * 2 + st] = v;
    }
}

// ---------------- conv5 MFMA (single-bf16 weights) + fused stats partials ----------------
template<int CIN, int COUT>
__launch_bounds__(256)
__global__ void conv5_mfma_k(const ushort_t* __restrict__ yin,
                             const ushort_t* __restrict__ whi,
                             ushort_t* __restrict__ yout,
                             float* __restrict__ sp) {
    __shared__ char smem[23552];
    ushort_t* hA = (ushort_t*)smem;             // [128][56] = 14336
    ushort_t* wH = (ushort_t*)(smem + 14336);   // [64][56]  = 7168
    float* sw = (float*)(smem + 21504);         // [4][64][2] = 2048
    const int tid = threadIdx.x;
    const int m0 = blockIdx.y * 128;
    const int o0 = blockIdx.x * 64;
    f32x4 acc[2][4];
#pragma unroll
    for (int mt = 0; mt < 2; mt++)
#pragma unroll
        for (int ot = 0; ot < 4; ot++) acc[mt][ot] = (f32x4){0.f, 0.f, 0.f, 0.f};
    const int lane = tid & 63, wv = tid >> 6;
    const int l15 = lane & 15, quad = lane >> 4;
    for (int kc = 0; kc < CIN; kc += 32) {
        __syncthreads();
#pragma unroll
        for (int i = 0; i < 2; i++) {
            int tt = tid + 256 * i;
            int mr = tt >> 2, cq = (tt & 3) * 8;
            *(uint4*)&hA[mr * 56 + cq] = *(const uint4*)(yin + (size_t)(m0 + mr) * CIN + kc + cq);
        }
        {
            int orow = tid >> 2, cq = (tid & 3) * 8;
            *(uint4*)&wH[orow * 56 + cq] = *(const uint4*)(whi + (size_t)(o0 + orow) * CIN + kc + cq);
        }
        __syncthreads();
        bf16x8 a0 = *(bf16x8*)&hA[(wv * 32 + l15) * 56 + quad * 8];
        bf16x8 a1 = *(bf16x8*)&hA[(wv * 32 + 16 + l15) * 56 + quad * 8];
#pragma unroll
        for (int ot = 0; ot < 4; ot++) {
            bf16x8 bh = *(bf16x8*)&wH[(ot * 16 + l15) * 56 + quad * 8];
            acc[0][ot] = __builtin_amdgcn_mfma_f32_16x16x32_bf16(a0, bh, acc[0][ot], 0, 0, 0);
            acc[1][ot] = __builtin_amdgcn_mfma_f32_16x16x32_bf16(a1, bh, acc[1][ot], 0, 0, 0);
        }
    }
#pragma unroll
    for (int ot = 0; ot < 4; ot++) {
        float sm = 0.0f, ss = 0.0f;
#pragma unroll
        for (int mt = 0; mt < 2; mt++)
#pragma unroll
            for (int r = 0; r < 4; r++) {
                float v = acc[mt][ot][r];
                sm += v; ss = fmaf(v, v, ss);
            }
        sm += __shfl_xor(sm, 16); sm += __shfl_xor(sm, 32);
        ss += __shfl_xor(ss, 16); ss += __shfl_xor(ss, 32);
        if (lane < 16) {
            sw[(wv * 64 + ot * 16 + l15) * 2 + 0] = sm;
            sw[(wv * 64 + ot * 16 + l15) * 2 + 1] = ss;
        }
    }
    __syncthreads();
    ushort_t* outT = (ushort_t*)smem;   // [128][72] = 18432 (< 21504, sw untouched)
#pragma unroll
    for (int mt = 0; mt < 2; mt++)
#pragma unroll
        for (int ot = 0; ot < 4; ot++)
#pragma unroll
            for (int r = 0; r < 4; r++)
                outT[(wv * 32 + mt * 16 + quad * 4 + r) * 72 + ot * 16 + l15] = f2bf(acc[mt][ot][r]);
    __syncthreads();
    int row = tid >> 1, half = tid & 1;
#pragma unroll
    for (int g = 0; g < 4; g++) {
        uint4 u = *(uint4*)&outT[row * 72 + half * 32 + g * 8];
        *(uint4*)(yout + (size_t)(m0 + row) * COUT + o0 + half * 32 + g * 8) = u;
    }
    if (tid < 128) {
        int ol = tid >> 1, st = tid & 1;
        float v = 0.0f;
#pragma unroll
        for (int w2 = 0; w2 < 4; w2++) v += sw[(w2 * 64 + ol) * 2 + st];
        size_t bid = (size_t)blockIdx.x * gridDim.y + blockIdx.y;
        sp[bid * 128 + ol * 2 + st] = v;
    }
}

// ---------------- fused conv (layers 2,3,4): 320m x BOo tiles, single-bf16 weights ----------------
// LESSONS: (r5/r6) runtime acc index -> scratch demotion: keep acc indexing static.
// (r7) cross-lane LDS round-trip needs __syncthreads() between write/read phases.
template<int CIN, int COUT, int BO, bool WRITEY>
__launch_bounds__(256, 2)
__global__ void conv_fused_k(const ushort_t* __restrict__ yin,
                             const ushort_t* __restrict__ whi,
                             const float* __restrict__ scale,
                             const float* __restrict__ shift,
                             ushort_t* __restrict__ yout,
                             float* __restrict__ rawmax, float* __restrict__ rawmin,
                             float* __restrict__ sp) {
    constexpr int NOT = BO / 16;
    __shared__ ushort_t hA[320 * 56];           // 35840 B; wreg overlays this
    __shared__ ushort_t wHs[BO * 56];
    __shared__ float scl[CIN], shf[CIN];
    __shared__ float sw[4 * BO * 2];
    const int tid = threadIdx.x;
    const int m0 = blockIdx.y * 320;            // 1024 m-tiles
    const int o0 = blockIdx.x * BO;
    for (int c = tid; c < CIN; c += 256) { scl[c] = scale[c]; shf[c] = shift[c]; }
    for (int i = tid; i < 4 * BO * 2; i += 256) sw[i] = 0.0f;
    f32x4 acc[5][NOT];
#pragma unroll
    for (int mt = 0; mt < 5; mt++)
#pragma unroll
        for (int ot = 0; ot < NOT; ot++) acc[mt][ot] = (f32x4){0.f, 0.f, 0.f, 0.f};
    const int lane = tid & 63, wv = tid >> 6;
    const int l15 = lane & 15, quad = lane >> 4;
    for (int kc = 0; kc < CIN; kc += 32) {
        __syncthreads();
#pragma unroll
        for (int i = 0; i < 5; i++) {
            int tt = tid + 256 * i;
            int mr = tt >> 2, cq = (tt & 3) * 8;
            uint4 u = *(const uint4*)(yin + (size_t)(m0 + mr) * CIN + kc + cq);
            float vv[8]; unpack8(u, vv);
#pragma unroll
            for (int e = 0; e < 8; e++)
                vv[e] = fmaxf(fmaf(vv[e], scl[kc + cq + e], shf[kc + cq + e]), 0.0f);
            u.x = pack2(vv[0], vv[1]); u.y = pack2(vv[2], vv[3]);
            u.z = pack2(vv[4], vv[5]); u.w = pack2(vv[6], vv[7]);
            *(uint4*)&hA[mr * 56 + cq] = u;
        }
        for (int t = tid; t < BO * 4; t += 256) {
            int row = t >> 2, cq = (t & 3) * 8;
            *(uint4*)&wHs[row * 56 + cq] = *(const uint4*)(whi + (size_t)(o0 + row) * CIN + kc + cq);
        }
        __syncthreads();
        bf16x8 a[5];
#pragma unroll
        for (int mt = 0; mt < 5; mt++)
            a[mt] = *(bf16x8*)&hA[(wv * 80 + mt * 16 + l15) * 56 + quad * 8];
#pragma unroll
        for (int ot = 0; ot < NOT; ot++) {
            bf16x8 bh = *(bf16x8*)&wHs[(ot * 16 + l15) * 56 + quad * 8];
#pragma unroll
            for (int mt = 0; mt < 5; mt++)
                acc[mt][ot] = __builtin_amdgcn_mfma_f32_16x16x32_bf16(a[mt], bh, acc[mt][ot], 0, 0, 0);
        }
    }
    __syncthreads();   // waves may still read hA/wHs; wreg overlays hA
    float* wreg = (float*)((char*)hA + wv * 6400);   // [80][20]
#pragma unroll
    for (int ot = 0; ot < NOT; ot++) {
#pragma unroll
        for (int mt = 0; mt < 5; mt++)
#pragma unroll
            for (int r = 0; r < 4; r++)
                wreg[(mt * 16 + quad * 4 + r) * 20 + l15] = acc[mt][ot][r];
        __syncthreads();   // cross-lane round-trip (r7 lesson)
        {
            int pp = quad;
            const float* rr = wreg + (pp * 20) * 20 + l15;
            float mx = rr[0], mn = rr[0], sm = 0.0f, ss = 0.0f;
#pragma unroll
            for (int q = 0; q < 20; q++) {
                float vv = rr[q * 20];
                mx = fmaxf(mx, vv); mn = fminf(mn, vv);
                sm += vv; ss = fmaf(vv, vv, ss);
            }
            int pt = blockIdx.y * 16 + wv * 4 + pp;
            int o = o0 + ot * 16 + l15;
            rawmax[(size_t)pt * COUT + o] = mx;
            rawmin[(size_t)pt * COUT + o] = mn;
            sm += __shfl_xor(sm, 16); sm += __shfl_xor(sm, 32);
            ss += __shfl_xor(ss, 16); ss += __shfl_xor(ss, 32);
            if (lane < 16) {
                sw[(wv * BO + ot * 16 + l15) * 2 + 0] += sm;
                sw[(wv * BO + ot * 16 + l15) * 2 + 1] += ss;
            }
        }
        if constexpr (WRITEY) {
#pragma unroll
            for (int it = 0; it < 3; it++) {
                int t = lane + it * 64;
                if (t < 160) {
                    int row = t >> 1, half = t & 1;
                    float4 f0 = *(float4*)&wreg[row * 20 + half * 8];
                    float4 f1 = *(float4*)&wreg[row * 20 + half * 8 + 4];
                    uint4 u;
                    u.x = pack2(f0.x, f0.y); u.y = pack2(f0.z, f0.w);
                    u.z = pack2(f1.x, f1.y); u.w = pack2(f1.z, f1.w);
                    *(uint4*)(yout + (size_t)(m0 + wv * 80 + row) * COUT + o0 + ot * 16 + half * 8) = u;
                }
            }
        }
        __syncthreads();
    }
    for (int t2 = tid; t2 < BO * 2; t2 += 256) {
        int ol = t2 >> 1, st = t2 & 1;
        float v = 0.0f;
#pragma unroll
        for (int w2 = 0; w2 < 4; w2++) v += sw[(w2 * BO + ol) * 2 + st];
        size_t bid = (size_t)blockIdx.x * 1024 + blockIdx.y;   // o-major
        sp[bid * (2 * BO) + ol * 2 + st] = v;
    }
}

// ---------------- reduce stats partials + finalize BN (all layers) ----------------
template<int BO, int MB>
__launch_bounds__(256)
__global__ void statsred_fin_k(const float* __restrict__ sp,
                               const float* __restrict__ g, const float* __restrict__ bb,
                               float* __restrict__ scale, float* __restrict__ shift,
                               double invcnt) {
    __shared__ double rs[256], rss[256];
    int o = blockIdx.x, tid = threadIdx.x;
    int oy = o / BO, ol = o % BO;
    double s = 0.0, ss = 0.0;
    for (int mb = tid; mb < MB; mb += 256) {
        size_t bid = (size_t)oy * MB + mb;
        s  += (double)sp[bid * (2 * BO) + ol * 2 + 0];
        ss += (double)sp[bid * (2 * BO) + ol * 2 + 1];
    }
    rs[tid] = s; rss[tid] = ss;
    __syncthreads();
    for (int st = 128; st; st >>= 1) {
        if (tid < st) { rs[tid] += rs[tid + st]; rss[tid] += rss[tid + st]; }
        __syncthreads();
    }
    if (tid == 0) {
        double m = rs[0] * invcnt;
        double v = rss[0] * invcnt - m * m;
        if (v < 0.0) v = 0.0;
        float sc = g[o] / sqrtf((float)v + 1e-5f);
        scale[o] = sc;
        shift[o] = bb[o] - (float)m * sc;
    }
}

// ---------------- pool finalize from raw max/min (BN monotone) -> xcat ----------------
template<int C8>
__launch_bounds__(256)
__global__ void pool_raw_k(const float* __restrict__ rawmax, const float* __restrict__ rawmin,
                           const float* __restrict__ scale, const float* __restrict__ shift,
                           ushort_t* __restrict__ xcat, int coff) {
    constexpr int COUT = C8 * 8;
    int gid = blockIdx.x * 256 + threadIdx.x;   // 16384 * C8
    int p = gid / C8, og = gid % C8;
    float sc[8], sh[8], mxv[8], mnv[8];
    *(float4*)&sc[0]  = *(const float4*)(scale + og * 8);
    *(float4*)&sc[4]  = *(const float4*)(scale + og * 8 + 4);
    *(float4*)&sh[0]  = *(const float4*)(shift + og * 8);
    *(float4*)&sh[4]  = *(const float4*)(shift + og * 8 + 4);
    *(float4*)&mxv[0] = *(const float4*)(rawmax + (size_t)p * COUT + og * 8);
    *(float4*)&mxv[4] = *(const float4*)(rawmax + (size_t)p * COUT + og * 8 + 4);
    *(float4*)&mnv[0] = *(const float4*)(rawmin + (size_t)p * COUT + og * 8);
    *(float4*)&mnv[4] = *(const float4*)(rawmin + (size_t)p * COUT + og * 8 + 4);
    float v[8];
#pragma unroll
    for (int e = 0; e < 8; e++) {
        float raw = (sc[e] >= 0.0f) ? mxv[e] : mnv[e];
        v[e] = fmaxf(fmaf(raw, sc[e], sh[e]), 0.0f);
    }
    uint4 u;
    u.x = pack2(v[0], v[1]); u.y = pack2(v[2], v[3]);
    u.z = pack2(v[4], v[5]); u.w = pack2(v[6], v[7]);
    *(uint4*)(xcat + (size_t)p * 512 + coff + og * 8) = u;
}

// ---------------- output: BN5+ReLU + transpose NHWC -> [b][c][n] fp32 ----------------
__launch_bounds__(256)
__global__ void out_k(const ushort_t* __restrict__ y5, const float* __restrict__ scale,
                      const float* __restrict__ shift, float* __restrict__ out) {
    __shared__ float tr[64 * 65];
    int tid = threadIdx.x;
    int n0 = blockIdx.x * 64, c0 = blockIdx.y * 64, b = blockIdx.z;
    int nl = tid >> 2, cq = (tid & 3) * 16;
    const ushort_t* src = y5 + (size_t)(b * 2048 + n0 + nl) * 512 + c0 + cq;
#pragma unroll
    for (int h = 0; h < 2; h++) {
        uint4 u = *(const uint4*)(src + h * 8);
        float vv[8]; unpack8(u, vv);
#pragma unroll
        for (int e = 0; e < 8; e++) {
            int c = cq + h * 8 + e;
            tr[c * 65 + nl] = fmaxf(fmaf(vv[e], scale[c0 + c], shift[c0 + c]), 0.0f);
        }
    }
    __syncthreads();
    int cl = tid >> 2, ng = (tid & 3) * 16;
#pragma unroll
    for (int g = 0; g < 4; g++) {
        float4 v = *(float4*)&tr[cl * 65 + ng + g * 4];
        *(float4*)(out + ((size_t)b * 512 + c0 + cl) * 2048 + n0 + ng + g * 4) = v;
    }
}

// ---------------- host ----------------
extern "C" void kernel_launch(void* const* d_in, const int* in_sizes, int n_in,
                              void* d_out, int out_size, void* d_ws, size_t ws_size,
                              hipStream_t stream) {
    (void)in_sizes; (void)n_in; (void)out_size;
    if (ws_size < WS_NEEDED) return;
    const float* x  = (const float*)d_in[0];
    const float* w1 = (const float*)d_in[1];
    const float* g1 = (const float*)d_in[2];
    const float* b1 = (const float*)d_in[3];
    const float* w2 = (const float*)d_in[4];
    const float* g2 = (const float*)d_in[5];
    const float* b2 = (const float*)d_in[6];
    const float* w3 = (const float*)d_in[7];
    const float* g3 = (const float*)d_in[8];
    const float* b3 = (const float*)d_in[9];
    const float* w4 = (const float*)d_in[10];
    const float* g4 = (const float*)d_in[11];
    const float* b4 = (const float*)d_in[12];
    const float* w5 = (const float*)d_in[13];
    const float* g5 = (const float*)d_in[14];
    const float* b5 = (const float*)d_in[15];

    char* ws = (char*)d_ws;
    float4* xt4 = (float4*)(ws + OFF_XT);
    int*   idx = (int*)(ws + OFF_IDX);
    ushort_t* wh2 = (ushort_t*)(ws + OFF_WH2);
    ushort_t* wh3 = (ushort_t*)(ws + OFF_WH3);
    ushort_t* wh4 = (ushort_t*)(ws + OFF_WH4);
    ushort_t* wh5 = (ushort_t*)(ws + OFF_WH5);
    ushort_t* y1 = (ushort_t*)(ws + OFF_REG0);
    ushort_t* y2 = (ushort_t*)(ws + OFF_REG1);
    ushort_t* y3 = (ushort_t*)(ws + OFF_REG0);
    ushort_t* y5 = (ushort_t*)(ws + OFF_REG0);
    ushort_t* xcat = (ushort_t*)(ws + OFF_XCAT);
    float* rawmax = (float*)(ws + OFF_RAWMAX);
    float* rawmin = (float*)(ws + OFF_RAWMIN);
    float* sp     = (float*)(ws + OFF_SP);

    float* scl[5]; float* shf[5];
    for (int l = 0; l < 5; l++) {
        scl[l] = (float*)(ws + OFF_SS + (size_t)l * 4096);
        shf[l] = scl[l] + 512;
    }

    prep_k<<<64, 256, 0, stream>>>(x, xt4);
    wsplit_all_k<<<1200, 256, 0, stream>>>(w2, wh2, w3, wh3, w4, wh4, w5, wh5);
    knn_k<<<2048, 256, 0, stream>>>(xt4, idx);

    // layer 1: fused graph-feature + conv + raw pool + stats (BO=64)
    conv1_fused_k<<<1024, 256, 0, stream>>>(xt4, idx, w1, y1, rawmax, rawmin, sp);
    statsred_fin_k<64, 1024><<<64, 256, 0, stream>>>(sp, g1, b1, scl[0], shf[0], 1.0 / 327680.0);
    pool_raw_k<8><<<512, 256, 0, stream>>>(rawmax, rawmin, scl[0], shf[0], xcat, 0);

    // layer 2: 64 -> 64 fused (BO=64)
    conv_fused_k<64, 64, 64, true><<<dim3(1, 1024), 256, 0, stream>>>(
        y1, wh2, scl[0], shf[0], y2, rawmax, rawmin, sp);
    statsred_fin_k<64, 1024><<<64, 256, 0, stream>>>(sp, g2, b2, scl[1], shf[1], 1.0 / 327680.0);
    pool_raw_k<8><<<512, 256, 0, stream>>>(rawmax, rawmin, scl[1], shf[1], xcat, 64);

    // layer 3: 64 -> 128 fused (BO=128)
    conv_fused_k<64, 128, 128, true><<<dim3(1, 1024), 256, 0, stream>>>(
        y2, wh3, scl[1], shf[1], y3, rawmax, rawmin, sp);
    statsred_fin_k<128, 1024><<<128, 256, 0, stream>>>(sp, g3, b3, scl[2], shf[2], 1.0 / 327680.0);
    pool_raw_k<16><<<1024, 256, 0, stream>>>(rawmax, rawmin, scl[2], shf[2], xcat, 128);

    // layer 4: 128 -> 256 fused (BO=128, 2 o-tiles)
    conv_fused_k<128, 256, 128, false><<<dim3(2, 1024), 256, 0, stream>>>(
        y3, wh4, scl[2], shf[2], nullptr, rawmax, rawmin, sp);
    statsred_fin_k<128, 1024><<<256, 256, 0, stream>>>(sp, g4, b4, scl[3], shf[3], 1.0 / 327680.0);
    pool_raw_k<32><<<2048, 256, 0, stream>>>(rawmax, rawmin, scl[3], shf[3], xcat, 256);

    // layer 5: 512 -> 512, single-bf16 weights, stats fused
    conv5_mfma_k<512, 512><<<dim3(8, 128), 256, 0, stream>>>(xcat, wh5, y5, sp);
    statsred_fin_k<64, 128><<<512, 256, 0, stream>>>(sp, g5, b5, scl[4], shf[4], 1.0 / 16384.0);
    out_k<<<dim3(32, 8, 8), 256, 0, stream>>>(y5, scl[4], shf[4], (float*)d_out);
}

// Round 4
// 414.864 us; speedup vs baseline: 1.2163x; 1.2163x over previous
//
#include <hip/hip_runtime.h>
#include <cstdint>
#include <cstddef>

// ---------------- constants ----------------
#define BATCH 8
#define NPTS 2048
#define KNN 20
#define M1 327680   // BATCH*NPTS*KNN
#define M2 16384    // BATCH*NPTS

typedef unsigned short ushort_t;
typedef unsigned long long u64;
typedef __attribute__((ext_vector_type(8))) short bf16x8;   // 8 bf16 = 4 VGPRs
typedef __attribute__((ext_vector_type(4))) float f32x4;    // MFMA acc
typedef __attribute__((ext_vector_type(2))) int int2v;

// ws layout (bytes) — total 181,121,024
// xt is float4 {x,y,z,xx}: 16384*16 = 262144 B.
#define OFF_XT    0UL          // 262144   float4 xt4[b*n]
#define OFF_IDX   262144UL     // 1310720  int idx[b*n][20]
#define OFF_WH2   1572864UL    // 8192   bf16 [64][64]
#define OFF_WH3   1589248UL    // 16384  bf16 [128][64]
#define OFF_WH4   1622016UL    // 65536  bf16 [256][128]
#define OFF_WH5   1753088UL    // 524288 bf16 [512][512]
#define OFF_SS    2842624UL    // 20480   5 x (512 scale + 512 shift) float
// REG0: y1 [M1][64] (41.9MB) -> y3 [M1][128] (83.9MB) -> y5 [M2][512] (16.8MB)
#define OFF_REG0  2863104UL    // 83886080
// REG1: y2 [M1][64] (41.9MB)
#define OFF_REG1  86749184UL   // 41943040
#define OFF_XCAT  128692224UL  // 16777216 xcat[M2][512] bf16
#define OFF_RAWMAX 145469440UL // 16777216 f32 [16384][<=256]
#define OFF_RAWMIN 162246656UL // 16777216
#define OFF_SP     179023872UL // 2097152  f32 partials
#define WS_NEEDED  181121024UL

// ---------------- helpers ----------------
__device__ __forceinline__ float bf2f(unsigned short u) {
    union { unsigned int i; float f; } c; c.i = ((unsigned int)u) << 16; return c.f;
}
__device__ __forceinline__ unsigned short f2bf(float f) {
    union { float f; unsigned int i; } c; c.f = f;
    unsigned int x = c.i;
    unsigned int r = (x + 0x7fffu + ((x >> 16) & 1u)) >> 16;  // RNE
    return (unsigned short)r;
}
__device__ __forceinline__ unsigned int pack2(float a, float b) {
    return (unsigned int)f2bf(a) | ((unsigned int)f2bf(b) << 16);
}
__device__ __forceinline__ void unpack8(uint4 u, float* v) {
    v[0] = bf2f((unsigned short)(u.x & 0xffffu)); v[1] = bf2f((unsigned short)(u.x >> 16));
    v[2] = bf2f((unsigned short)(u.y & 0xffffu)); v[3] = bf2f((unsigned short)(u.y >> 16));
    v[4] = bf2f((unsigned short)(u.z & 0xffffu)); v[5] = bf2f((unsigned short)(u.z >> 16));
    v[6] = bf2f((unsigned short)(u.w & 0xffffu)); v[7] = bf2f((unsigned short)(u.w >> 16));
}

// ---------------- prep: transpose x, compute xx, pack as float4 ----------------
__global__ void prep_k(const float* __restrict__ x, float4* __restrict__ xt4) {
    int t = blockIdx.x * 256 + threadIdx.x;   // 16384
    int b = t >> 11, n = t & 2047;
    float v0 = x[((size_t)b * 3 + 0) * NPTS + n];
    float v1 = x[((size_t)b * 3 + 1) * NPTS + n];
    float v2 = x[((size_t)b * 3 + 2) * NPTS + n];
    float xxv = __fadd_rn(__fadd_rn(__fmul_rn(v0, v0), __fmul_rn(v1, v1)), __fmul_rn(v2, v2));
    xt4[t] = make_float4(v0, v1, v2, xxv);
}

// ---------------- weight prep: single bf16 for all MFMA layers ----------------
__global__ void wsplit_all_k(const float* __restrict__ w2, ushort_t* __restrict__ wh2,
                             const float* __restrict__ w3, ushort_t* __restrict__ wh3,
                             const float* __restrict__ w4, ushort_t* __restrict__ wh4,
                             const float* __restrict__ w5, ushort_t* __restrict__ wh5) {
    int t = blockIdx.x * 256 + threadIdx.x;   // 307200 total
    if (t < 4096)        { wh2[t] = f2bf(w2[t]); }
    else if (t < 12288)  { int o = t - 4096;  wh3[o] = f2bf(w3[o]); }
    else if (t < 45056)  { int o = t - 12288; wh4[o] = f2bf(w4[o]); }
    else                 { int o = t - 45056; wh5[o] = f2bf(w5[o]); }
}

// ---------------- knn: 2 points per wave (r16 proven version) ----------------
// r14: __shfl_xor butterfly -> DS saturation; DPP row_ror (VALU only).
// r15: u64 sortable keys -> single cmp_u64 merges.
// r16: permlane swaps all-reduce, myj accumulator, float4 xt, unroll 1. (97.5 us)
// r17 LESSON: f64-key half-wave variant -> VGPR 132, occupancy 11%, 166 us.
//   Any knn variant pushing VGPR past ~96 loses more to occupancy than it
//   gains in issue count; 64-bit DPP operand paths are a register trap.

__device__ __forceinline__ unsigned okey(float f) {
    int u = __float_as_int(f);
    return (unsigned)(u ^ ((u >> 31) | 0x80000000));
}

#define DPP_ROR(x, n) __builtin_amdgcn_update_dpp(0, (x), 0x120 + (n), 0xf, 0xf, true)

template<int N>
__device__ __forceinline__ void ror_max(u64 &k) {
    unsigned h = (unsigned)DPP_ROR((int)(unsigned)(k >> 32), N);
    unsigned lo = (unsigned)DPP_ROR((int)(unsigned)k, N);
    u64 o = ((u64)h << 32) | lo;
    if (o > k) k = o;
}

// merge lane i with lane i^16 (VALU pipe, no DS)
__device__ __forceinline__ void swap16_max(u64 &k) {
    int2v ph = __builtin_amdgcn_permlane16_swap((int)(unsigned)(k >> 32), (int)(unsigned)(k >> 32), false, false);
    int2v pl = __builtin_amdgcn_permlane16_swap((int)(unsigned)k, (int)(unsigned)k, false, false);
    u64 a = ((u64)(unsigned)ph.x << 32) | (unsigned)pl.x;
    u64 b = ((u64)(unsigned)ph.y << 32) | (unsigned)pl.y;
    k = (b > a) ? b : a;
}

// merge lane i with lane i^32 (VALU pipe, no DS)
__device__ __forceinline__ void swap32_max(u64 &k) {
    int2v ph = __builtin_amdgcn_permlane32_swap((int)(unsigned)(k >> 32), (int)(unsigned)(k >> 32), false, false);
    int2v pl = __builtin_amdgcn_permlane32_swap((int)(unsigned)k, (int)(unsigned)k, false, false);
    u64 a = ((u64)(unsigned)ph.x << 32) | (unsigned)pl.x;
    u64 b = ((u64)(unsigned)ph.y << 32) | (unsigned)pl.y;
    k = (b > a) ? b : a;
}

template<int G>
__device__ __forceinline__ void knn_rescan(float (&v)[32], u64 (&gk)[4],
                                           bool own, int qw, unsigned laneC) {
#pragma unroll
    for (int q = G * 8; q < G * 8 + 8; q++)
        if (own && q == qw) v[q] = -3.4e38f;
    float m = v[G * 8]; int qi = G * 8;
#pragma unroll
    for (int q = G * 8 + 1; q < G * 8 + 8; q++)
        if (v[q] > m) { m = v[q]; qi = q; }
    gk[G] = ((u64)okey(m) << 32) | (laneC - (unsigned)(qi << 6));
}

__device__ __forceinline__ void knn_rescan_any(float (&v)[32], u64 (&gk)[4],
                                               int j, int l, unsigned laneC) {
    int qw = j >> 6;
    bool own = (l == (j & 63));
    int gw = qw >> 3;
    if (gw == 0)      knn_rescan<0>(v, gk, own, qw, laneC);
    else if (gw == 1) knn_rescan<1>(v, gk, own, qw, laneC);
    else if (gw == 2) knn_rescan<2>(v, gk, own, qw, laneC);
    else              knn_rescan<3>(v, gk, own, qw, laneC);
}

__launch_bounds__(256)
__global__ void knn_k(const float4* __restrict__ xt4, int* __restrict__ idx) {
    int tid = threadIdx.x;
    int l = tid & 63, wv = tid >> 6;
    int pidA = blockIdx.x * 8 + wv * 2;
    int pidB = pidA + 1;
    int b = pidA >> 11;
    const float4* xb4 = xt4 + (size_t)b * NPTS;
    int iA = pidA & 2047, iB = pidB & 2047;
    float4 PA = xb4[iA];
    float4 PB = xb4[iB];
    float vA[32], vB[32];
#pragma unroll
    for (int q = 0; q < 32; q++) {
        float4 p = xb4[l + q * 64];
        float dA = __fadd_rn(__fadd_rn(__fmul_rn(PA.x, p.x), __fmul_rn(PA.y, p.y)), __fmul_rn(PA.z, p.z));
        float dB = __fadd_rn(__fadd_rn(__fmul_rn(PB.x, p.x), __fmul_rn(PB.y, p.y)), __fmul_rn(PB.z, p.z));
        vA[q] = __fsub_rn(__fsub_rn(-PA.w, __fmul_rn(-2.0f, dA)), p.w);
        vB[q] = __fsub_rn(__fsub_rn(-PB.w, __fmul_rn(-2.0f, dB)), p.w);
    }
    unsigned laneC = (unsigned)(2047 - l);
    u64 gkA[4], gkB[4];
#pragma unroll
    for (int g = 0; g < 4; g++) {
        float mA = vA[g * 8]; int qA = g * 8;
        float mB = vB[g * 8]; int qB = g * 8;
#pragma unroll
        for (int q = g * 8 + 1; q < g * 8 + 8; q++) {
            if (vA[q] > mA) { mA = vA[q]; qA = q; }
            if (vB[q] > mB) { mB = vB[q]; qB = q; }
        }
        gkA[g] = ((u64)okey(mA) << 32) | (laneC - (unsigned)(qA << 6));
        gkB[g] = ((u64)okey(mB) << 32) | (laneC - (unsigned)(qB << 6));
    }
    int* outA = idx + (size_t)pidA * KNN;
    int* outB = idx + (size_t)pidB * KNN;
    unsigned myj = 0;
#pragma unroll 1
    for (int t = 0; t < KNN; t++) {
        // --- branch-free merge + all-reduce, A and B interleaved ---
        u64 kA = gkA[0], kB = gkB[0];
#pragma unroll
        for (int g = 1; g < 4; g++) {
            if (gkA[g] > kA) kA = gkA[g];
            if (gkB[g] > kB) kB = gkB[g];
        }
        ror_max<1>(kA); ror_max<1>(kB);
        ror_max<2>(kA); ror_max<2>(kB);
        ror_max<4>(kA); ror_max<4>(kB);
        ror_max<8>(kA); ror_max<8>(kB);
        swap16_max(kA); swap16_max(kB);
        swap32_max(kA); swap32_max(kB);
        // every lane now holds the global winner key; low 32 bits = 2047 - j
        unsigned jAv = 2047u - (unsigned)kA;
        unsigned jBv = 2047u - (unsigned)kB;
        myj = (l == t) ? jAv : myj;
        myj = (l == t + 32) ? jBv : myj;
        if (t == KNN - 1) break;
        int jA = 2047 - (int)(unsigned)__builtin_amdgcn_readfirstlane((int)(unsigned)kA);
        int jB = 2047 - (int)(unsigned)__builtin_amdgcn_readfirstlane((int)(unsigned)kB);
        knn_rescan_any(vA, gkA, jA, l, laneC);
        knn_rescan_any(vB, gkB, jB, l, laneC);
    }
    if (l < KNN) outA[l] = (int)myj;
    else if (l >= 32 && l < 32 + KNN) outB[l - 32] = (int)myj;
}

// ---------------- conv1 fused MFMA: graph-feature stager (K=32 zero-padded) + conv_fused
// epilogue (raw max/min per k-window + fp32 stats partials + y1 write). BO=64.
__launch_bounds__(256, 2)
__global__ void conv1_fused_k(const float4* __restrict__ xt4, const int* __restrict__ idx,
                              const float* __restrict__ w1, ushort_t* __restrict__ y1,
                              float* __restrict__ rawmax, float* __restrict__ rawmin,
                              float* __restrict__ sp) {
    __shared__ ushort_t hA[320 * 56];           // wreg overlays this in epilogue
    __shared__ ushort_t wHs[64 * 56];
    __shared__ float sw[4 * 64 * 2];
    const int tid = threadIdx.x;
    const int m0 = blockIdx.x * 320;            // 1024 m-tiles
    for (int i = tid; i < 512; i += 256) sw[i] = 0.0f;
    {
        int row = tid >> 2, seg = tid & 3;
        uint4 u = make_uint4(0, 0, 0, 0);
        if (seg == 0) {
            const float* wr = w1 + row * 6;
            u.x = pack2(wr[0], wr[1]);
            u.y = pack2(wr[2], wr[3]);
            u.z = pack2(wr[4], wr[5]);
        }
        *(uint4*)&wHs[row * 56 + seg * 8] = u;
    }
    for (int r = tid; r < 320; r += 256) {
        int m = m0 + r;
        int nb = m / KNN;
        int b = nb >> 11;
        int j = idx[m];
        float4 PI = xt4[nb];
        float4 PJ = xt4[(size_t)(b * NPTS + j)];
        uint4 u;
        u.x = pack2(PJ.x - PI.x, PJ.y - PI.y);
        u.y = pack2(PJ.z - PI.z, PI.x);
        u.z = pack2(PI.y, PI.z);
        u.w = 0;
        uint4 z = make_uint4(0, 0, 0, 0);
        *(uint4*)&hA[r * 56 + 0]  = u;
        *(uint4*)&hA[r * 56 + 8]  = z;
        *(uint4*)&hA[r * 56 + 16] = z;
        *(uint4*)&hA[r * 56 + 24] = z;
    }
    __syncthreads();
    const int lane = tid & 63, wv = tid >> 6;
    const int l15 = lane & 15, quad = lane >> 4;
    f32x4 acc[5][4];
#pragma unroll
    for (int mt = 0; mt < 5; mt++)
#pragma unroll
        for (int ot = 0; ot < 4; ot++) acc[mt][ot] = (f32x4){0.f, 0.f, 0.f, 0.f};
    bf16x8 a[5];
#pragma unroll
    for (int mt = 0; mt < 5; mt++)
        a[mt] = *(bf16x8*)&hA[(wv * 80 + mt * 16 + l15) * 56 + quad * 8];
#pragma unroll
    for (int ot = 0; ot < 4; ot++) {
        bf16x8 bh = *(bf16x8*)&wHs[(ot * 16 + l15) * 56 + quad * 8];
#pragma unroll
        for (int mt = 0; mt < 5; mt++)
            acc[mt][ot] = __builtin_amdgcn_mfma_f32_16x16x32_bf16(a[mt], bh, acc[mt][ot], 0, 0, 0);
    }
    __syncthreads();   // wreg overlays hA
    float* wreg = (float*)((char*)hA + wv * 6400);   // [80][20]
#pragma unroll
    for (int ot = 0; ot < 4; ot++) {
#pragma unroll
        for (int mt = 0; mt < 5; mt++)
#pragma unroll
            for (int r = 0; r < 4; r++)
                wreg[(mt * 16 + quad * 4 + r) * 20 + l15] = acc[mt][ot][r];
        __syncthreads();   // cross-lane round-trip (r7 lesson)
        {
            int pp = quad;
            const float* rr = wreg + (pp * 20) * 20 + l15;
            float mx = rr[0], mn = rr[0], sm = 0.0f, ss = 0.0f;
#pragma unroll
            for (int q = 0; q < 20; q++) {
                float vv = rr[q * 20];
                mx = fmaxf(mx, vv); mn = fminf(mn, vv);
                sm += vv; ss = fmaf(vv, vv, ss);
            }
            int pt = blockIdx.x * 16 + wv * 4 + pp;
            int o = ot * 16 + l15;
            rawmax[(size_t)pt * 64 + o] = mx;
            rawmin[(size_t)pt * 64 + o] = mn;
            sm += __shfl_xor(sm, 16); sm += __shfl_xor(sm, 32);
            ss += __shfl_xor(ss, 16); ss += __shfl_xor(ss, 32);
            if (lane < 16) {
                sw[(wv * 64 + ot * 16 + l15) * 2 + 0] += sm;
                sw[(wv * 64 + ot * 16 + l15) * 2 + 1] += ss;
            }
        }
#pragma unroll
        for (int it = 0; it < 3; it++) {
            int t = lane + it * 64;
            if (t < 160) {
                int row = t >> 1, half = t & 1;
                float4 f0 = *(float4*)&wreg[row * 20 + half * 8];
                float4 f1 = *(float4*)&wreg[row * 20 + half * 8 + 4];
                uint4 u;
                u.x = pack2(f0.x, f0.y); u.y = pack2(f0.z, f0.w);
                u.z = pack2(f1.x, f1.y); u.w = pack2(f1.z, f1.w);
                *(uint4*)(y1 + (size_t)(m0 + wv * 80 + row) * 64 + ot * 16 + half * 8) = u;
            }
        }
        __syncthreads();
    }
    if (tid < 128) {
        int ol = tid >> 1, st = tid & 1;
        float v = 0.0f;
#pragma unroll
        for (int w2 = 0; w2 < 4; w2++) v += sw[(w2 * 64 + ol) * 2 + st];
        sp[(size_t)blockIdx.x * 128 + ol * 2 + st] = v;
    }
}

// ---------------- conv5 MFMA (single-bf16 weights) + fused stats partials ----------------
// r18: o-tile widened 64->128 (grid 8x128 -> 4x128): halves xcat HBM re-reads
// (8x -> 4x, ~67MB saved; bx-blocks land on different XCDs so no L2 sharing).
template<int CIN, int COUT>
__launch_bounds__(256)
__global__ void conv5_mfma_k(const ushort_t* __restrict__ yin,
                             const ushort_t* __restrict__ whi,
                             ushort_t* __restrict__ yout,
                             float* __restrict__ sp) {
    __shared__ char smem[38912];
    ushort_t* hA = (ushort_t*)smem;             // [128][56] = 14336
    ushort_t* wH = (ushort_t*)(smem + 14336);   // [128][56] = 14336
    float* sw = (float*)(smem + 34816);         // [4][128][2] = 4096
    const int tid = threadIdx.x;
    const int m0 = blockIdx.y * 128;
    const int o0 = blockIdx.x * 128;
    f32x4 acc[2][8];
#pragma unroll
    for (int mt = 0; mt < 2; mt++)
#pragma unroll
        for (int ot = 0; ot < 8; ot++) acc[mt][ot] = (f32x4){0.f, 0.f, 0.f, 0.f};
    const int lane = tid & 63, wv = tid >> 6;
    const int l15 = lane & 15, quad = lane >> 4;
    for (int kc = 0; kc < CIN; kc += 32) {
        __syncthreads();
#pragma unroll
        for (int i = 0; i < 2; i++) {
            int tt = tid + 256 * i;
            int mr = tt >> 2, cq = (tt & 3) * 8;
            *(uint4*)&hA[mr * 56 + cq] = *(const uint4*)(yin + (size_t)(m0 + mr) * CIN + kc + cq);
        }
#pragma unroll
        for (int i = 0; i < 2; i++) {
            int tt = tid + 256 * i;
            int orow = tt >> 2, cq = (tt & 3) * 8;
            *(uint4*)&wH[orow * 56 + cq] = *(const uint4*)(whi + (size_t)(o0 + orow) * CIN + kc + cq);
        }
        __syncthreads();
        bf16x8 a0 = *(bf16x8*)&hA[(wv * 32 + l15) * 56 + quad * 8];
        bf16x8 a1 = *(bf16x8*)&hA[(wv * 32 + 16 + l15) * 56 + quad * 8];
#pragma unroll
        for (int ot = 0; ot < 8; ot++) {
            bf16x8 bh = *(bf16x8*)&wH[(ot * 16 + l15) * 56 + quad * 8];
            acc[0][ot] = __builtin_amdgcn_mfma_f32_16x16x32_bf16(a0, bh, acc[0][ot], 0, 0, 0);
            acc[1][ot] = __builtin_amdgcn_mfma_f32_16x16x32_bf16(a1, bh, acc[1][ot], 0, 0, 0);
        }
    }
#pragma unroll
    for (int ot = 0; ot < 8; ot++) {
        float sm = 0.0f, ss = 0.0f;
#pragma unroll
        for (int mt = 0; mt < 2; mt++)
#pragma unroll
            for (int r = 0; r < 4; r++) {
                float v = acc[mt][ot][r];
                sm += v; ss = fmaf(v, v, ss);
            }
        sm += __shfl_xor(sm, 16); sm += __shfl_xor(sm, 32);
        ss += __shfl_xor(ss, 16); ss += __shfl_xor(ss, 32);
        if (lane < 16) {
            sw[(wv * 128 + ot * 16 + l15) * 2 + 0] = sm;
            sw[(wv * 128 + ot * 16 + l15) * 2 + 1] = ss;
        }
    }
    __syncthreads();
    ushort_t* outT = (ushort_t*)smem;   // [128][136] = 34816 (sw at 34816 untouched)
#pragma unroll
    for (int mt = 0; mt < 2; mt++)
#pragma unroll
        for (int ot = 0; ot < 8; ot++)
#pragma unroll
            for (int r = 0; r < 4; r++)
                outT[(wv * 32 + mt * 16 + quad * 4 + r) * 136 + ot * 16 + l15] = f2bf(acc[mt][ot][r]);
    __syncthreads();
    int row = tid >> 1, half = tid & 1;
#pragma unroll
    for (int g = 0; g < 8; g++) {
        uint4 u = *(uint4*)&outT[row * 136 + half * 64 + g * 8];
        *(uint4*)(yout + (size_t)(m0 + row) * COUT + o0 + half * 64 + g * 8) = u;
    }
    {
        int ol = tid >> 1, st = tid & 1;
        float v = 0.0f;
#pragma unroll
        for (int w2 = 0; w2 < 4; w2++) v += sw[(w2 * 128 + ol) * 2 + st];
        size_t bid = (size_t)blockIdx.x * gridDim.y + blockIdx.y;
        sp[bid * 256 + ol * 2 + st] = v;
    }
}

// ---------------- fused conv (layers 2,3,4): 320m x BOo tiles, single-bf16 weights ----------------
// LESSONS: (r5/r6) runtime acc index -> scratch demotion: keep acc indexing static.
// (r7) cross-lane LDS round-trip needs __syncthreads() between write/read phases.
template<int CIN, int COUT, int BO, bool WRITEY>
__launch_bounds__(256, 2)
__global__ void conv_fused_k(const ushort_t* __restrict__ yin,
                             const ushort_t* __restrict__ whi,
                             const float* __restrict__ scale,
                             const float* __restrict__ shift,
                             ushort_t* __restrict__ yout,
                             float* __restrict__ rawmax, float* __restrict__ rawmin,
                             float* __restrict__ sp) {
    constexpr int NOT = BO / 16;
    __shared__ ushort_t hA[320 * 56];           // 35840 B; wreg overlays this
    __shared__ ushort_t wHs[BO * 56];
    __shared__ float scl[CIN], shf[CIN];
    __shared__ float sw[4 * BO * 2];
    const int tid = threadIdx.x;
    const int m0 = blockIdx.y * 320;            // 1024 m-tiles
    const int o0 = blockIdx.x * BO;
    for (int c = tid; c < CIN; c += 256) { scl[c] = scale[c]; shf[c] = shift[c]; }
    for (int i = tid; i < 4 * BO * 2; i += 256) sw[i] = 0.0f;
    f32x4 acc[5][NOT];
#pragma unroll
    for (int mt = 0; mt < 5; mt++)
#pragma unroll
        for (int ot = 0; ot < NOT; ot++) acc[mt][ot] = (f32x4){0.f, 0.f, 0.f, 0.f};
    const int lane = tid & 63, wv = tid >> 6;
    const int l15 = lane & 15, quad = lane >> 4;
    for (int kc = 0; kc < CIN; kc += 32) {
        __syncthreads();
#pragma unroll
        for (int i = 0; i < 5; i++) {
            int tt = tid + 256 * i;
            int mr = tt >> 2, cq = (tt & 3) * 8;
            uint4 u = *(const uint4*)(yin + (size_t)(m0 + mr) * CIN + kc + cq);
            float vv[8]; unpack8(u, vv);
#pragma unroll
            for (int e = 0; e < 8; e++)
                vv[e] = fmaxf(fmaf(vv[e], scl[kc + cq + e], shf[kc + cq + e]), 0.0f);
            u.x = pack2(vv[0], vv[1]); u.y = pack2(vv[2], vv[3]);
            u.z = pack2(vv[4], vv[5]); u.w = pack2(vv[6], vv[7]);
            *(uint4*)&hA[mr * 56 + cq] = u;
        }
        for (int t = tid; t < BO * 4; t += 256) {
            int row = t >> 2, cq = (t & 3) * 8;
            *(uint4*)&wHs[row * 56 + cq] = *(const uint4*)(whi + (size_t)(o0 + row) * CIN + kc + cq);
        }
        __syncthreads();
        bf16x8 a[5];
#pragma unroll
        for (int mt = 0; mt < 5; mt++)
            a[mt] = *(bf16x8*)&hA[(wv * 80 + mt * 16 + l15) * 56 + quad * 8];
#pragma unroll
        for (int ot = 0; ot < NOT; ot++) {
            bf16x8 bh = *(bf16x8*)&wHs[(ot * 16 + l15) * 56 + quad * 8];
#pragma unroll
            for (int mt = 0; mt < 5; mt++)
                acc[mt][ot] = __builtin_amdgcn_mfma_f32_16x16x32_bf16(a[mt], bh, acc[mt][ot], 0, 0, 0);
        }
    }
    __syncthreads();   // waves may still read hA/wHs; wreg overlays hA
    float* wreg = (float*)((char*)hA + wv * 6400);   // [80][20]
#pragma unroll
    for (int ot = 0; ot < NOT; ot++) {
#pragma unroll
        for (int mt = 0; mt < 5; mt++)
#pragma unroll
            for (int r = 0; r < 4; r++)
                wreg[(mt * 16 + quad * 4 + r) * 20 + l15] = acc[mt][ot][r];
        __syncthreads();   // cross-lane round-trip (r7 lesson)
        {
            int pp = quad;
            const float* rr = wreg + (pp * 20) * 20 + l15;
            float mx = rr[0], mn = rr[0], sm = 0.0f, ss = 0.0f;
#pragma unroll
            for (int q = 0; q < 20; q++) {
                float vv = rr[q * 20];
                mx = fmaxf(mx, vv); mn = fminf(mn, vv);
                sm += vv; ss = fmaf(vv, vv, ss);
            }
            int pt = blockIdx.y * 16 + wv * 4 + pp;
            int o = o0 + ot * 16 + l15;
            rawmax[(size_t)pt * COUT + o] = mx;
            rawmin[(size_t)pt * COUT + o] = mn;
            sm += __shfl_xor(sm, 16); sm += __shfl_xor(sm, 32);
            ss += __shfl_xor(ss, 16); ss += __shfl_xor(ss, 32);
            if (lane < 16) {
                sw[(wv * BO + ot * 16 + l15) * 2 + 0] += sm;
                sw[(wv * BO + ot * 16 + l15) * 2 + 1] += ss;
            }
        }
        if constexpr (WRITEY) {
#pragma unroll
            for (int it = 0; it < 3; it++) {
                int t = lane + it * 64;
                if (t < 160) {
                    int row = t >> 1, half = t & 1;
                    float4 f0 = *(float4*)&wreg[row * 20 + half * 8];
                    float4 f1 = *(float4*)&wreg[row * 20 + half * 8 + 4];
                    uint4 u;
                    u.x = pack2(f0.x, f0.y); u.y = pack2(f0.z, f0.w);
                    u.z = pack2(f1.x, f1.y); u.w = pack2(f1.z, f1.w);
                    *(uint4*)(yout + (size_t)(m0 + wv * 80 + row) * COUT + o0 + ot * 16 + half * 8) = u;
                }
            }
        }
        __syncthreads();
    }
    for (int t2 = tid; t2 < BO * 2; t2 += 256) {
        int ol = t2 >> 1, st = t2 & 1;
        float v = 0.0f;
#pragma unroll
        for (int w2 = 0; w2 < 4; w2++) v += sw[(w2 * BO + ol) * 2 + st];
        size_t bid = (size_t)blockIdx.x * 1024 + blockIdx.y;   // o-major
        sp[bid * (2 * BO) + ol * 2 + st] = v;
    }
}

// ---------------- reduce stats partials + finalize BN (all layers) ----------------
template<int BO, int MB>
__launch_bounds__(256)
__global__ void statsred_fin_k(const float* __restrict__ sp,
                               const float* __restrict__ g, const float* __restrict__ bb,
                               float* __restrict__ scale, float* __restrict__ shift,
                               double invcnt) {
    __shared__ double rs[256], rss[256];
    int o = blockIdx.x, tid = threadIdx.x;
    int oy = o / BO, ol = o % BO;
    double s = 0.0, ss = 0.0;
    for (int mb = tid; mb < MB; mb += 256) {
        size_t bid = (size_t)oy * MB + mb;
        s  += (double)sp[bid * (2 * BO) + ol * 2 + 0];
        ss += (double)sp[bid * (2 * BO) + ol * 2 + 1];
    }
    rs[tid] = s; rss[tid] = ss;
    __syncthreads();
    for (int st = 128; st; st >>= 1) {
        if (tid < st) { rs[tid] += rs[tid + st]; rss[tid] += rss[tid + st]; }
        __syncthreads();
    }
    if (tid == 0) {
        double m = rs[0] * invcnt;
        double v = rss[0] * invcnt - m * m;
        if (v < 0.0) v = 0.0;
        float sc = g[o] / sqrtf((float)v + 1e-5f);
        scale[o] = sc;
        shift[o] = bb[o] - (float)m * sc;
    }
}

// ---------------- pool finalize from raw max/min (BN monotone) -> xcat ----------------
template<int C8>
__launch_bounds__(256)
__global__ void pool_raw_k(const float* __restrict__ rawmax, const float* __restrict__ rawmin,
                           const float* __restrict__ scale, const float* __restrict__ shift,
                           ushort_t* __restrict__ xcat, int coff) {
    constexpr int COUT = C8 * 8;
    int gid = blockIdx.x * 256 + threadIdx.x;   // 16384 * C8
    int p = gid / C8, og = gid % C8;
    float sc[8], sh[8], mxv[8], mnv[8];
    *(float4*)&sc[0]  = *(const float4*)(scale + og * 8);
    *(float4*)&sc[4]  = *(const float4*)(scale + og * 8 + 4);
    *(float4*)&sh[0]  = *(const float4*)(shift + og * 8);
    *(float4*)&sh[4]  = *(const float4*)(shift + og * 8 + 4);
    *(float4*)&mxv[0] = *(const float4*)(rawmax + (size_t)p * COUT + og * 8);
    *(float4*)&mxv[4] = *(const float4*)(rawmax + (size_t)p * COUT + og * 8 + 4);
    *(float4*)&mnv[0] = *(const float4*)(rawmin + (size_t)p * COUT + og * 8);
    *(float4*)&mnv[4] = *(const float4*)(rawmin + (size_t)p * COUT + og * 8 + 4);
    float v[8];
#pragma unroll
    for (int e = 0; e < 8; e++) {
        float raw = (sc[e] >= 0.0f) ? mxv[e] : mnv[e];
        v[e] = fmaxf(fmaf(raw, sc[e], sh[e]), 0.0f);
    }
    uint4 u;
    u.x = pack2(v[0], v[1]); u.y = pack2(v[2], v[3]);
    u.z = pack2(v[4], v[5]); u.w = pack2(v[6], v[7]);
    *(uint4*)(xcat + (size_t)p * 512 + coff + og * 8) = u;
}

// ---------------- output: BN5+ReLU + transpose NHWC -> [b][c][n] fp32 ----------------
__launch_bounds__(256)
__global__ void out_k(const ushort_t* __restrict__ y5, const float* __restrict__ scale,
                      const float* __restrict__ shift, float* __restrict__ out) {
    __shared__ float tr[64 * 65];
    int tid = threadIdx.x;
    int n0 = blockIdx.x * 64, c0 = blockIdx.y * 64, b = blockIdx.z;
    int nl = tid >> 2, cq = (tid & 3) * 16;
    const ushort_t* src = y5 + (size_t)(b * 2048 + n0 + nl) * 512 + c0 + cq;
#pragma unroll
    for (int h = 0; h < 2; h++) {
        uint4 u = *(const uint4*)(src + h * 8);
        float vv[8]; unpack8(u, vv);
#pragma unroll
        for (int e = 0; e < 8; e++) {
            int c = cq + h * 8 + e;
            tr[c * 65 + nl] = fmaxf(fmaf(vv[e], scale[c0 + c], shift[c0 + c]), 0.0f);
        }
    }
    __syncthreads();
    int cl = tid >> 2, ng = (tid & 3) * 16;
#pragma unroll
    for (int g = 0; g < 4; g++) {
        float4 v = *(float4*)&tr[cl * 65 + ng + g * 4];
        *(float4*)(out + ((size_t)b * 512 + c0 + cl) * 2048 + n0 + ng + g * 4) = v;
    }
}

// ---------------- host ----------------
extern "C" void kernel_launch(void* const* d_in, const int* in_sizes, int n_in,
                              void* d_out, int out_size, void* d_ws, size_t ws_size,
                              hipStream_t stream) {
    (void)in_sizes; (void)n_in; (void)out_size;
    if (ws_size < WS_NEEDED) return;
    const float* x  = (const float*)d_in[0];
    const float* w1 = (const float*)d_in[1];
    const float* g1 = (const float*)d_in[2];
    const float* b1 = (const float*)d_in[3];
    const float* w2 = (const float*)d_in[4];
    const float* g2 = (const float*)d_in[5];
    const float* b2 = (const float*)d_in[6];
    const float* w3 = (const float*)d_in[7];
    const float* g3 = (const float*)d_in[8];
    const float* b3 = (const float*)d_in[9];
    const float* w4 = (const float*)d_in[10];
    const float* g4 = (const float*)d_in[11];
    const float* b4 = (const float*)d_in[12];
    const float* w5 = (const float*)d_in[13];
    const float* g5 = (const float*)d_in[14];
    const float* b5 = (const float*)d_in[15];

    char* ws = (char*)d_ws;
    float4* xt4 = (float4*)(ws + OFF_XT);
    int*   idx = (int*)(ws + OFF_IDX);
    ushort_t* wh2 = (ushort_t*)(ws + OFF_WH2);
    ushort_t* wh3 = (ushort_t*)(ws + OFF_WH3);
    ushort_t* wh4 = (ushort_t*)(ws + OFF_WH4);
    ushort_t* wh5 = (ushort_t*)(ws + OFF_WH5);
    ushort_t* y1 = (ushort_t*)(ws + OFF_REG0);
    ushort_t* y2 = (ushort_t*)(ws + OFF_REG1);
    ushort_t* y3 = (ushort_t*)(ws + OFF_REG0);
    ushort_t* y5 = (ushort_t*)(ws + OFF_REG0);
    ushort_t* xcat = (ushort_t*)(ws + OFF_XCAT);
    float* rawmax = (float*)(ws + OFF_RAWMAX);
    float* rawmin = (float*)(ws + OFF_RAWMIN);
    float* sp     = (float*)(ws + OFF_SP);

    float* scl[5]; float* shf[5];
    for (int l = 0; l < 5; l++) {
        scl[l] = (float*)(ws + OFF_SS + (size_t)l * 4096);
        shf[l] = scl[l] + 512;
    }

    prep_k<<<64, 256, 0, stream>>>(x, xt4);
    wsplit_all_k<<<1200, 256, 0, stream>>>(w2, wh2, w3, wh3, w4, wh4, w5, wh5);
    knn_k<<<2048, 256, 0, stream>>>(xt4, idx);

    // layer 1: fused graph-feature + conv + raw pool + stats (BO=64)
    conv1_fused_k<<<1024, 256, 0, stream>>>(xt4, idx, w1, y1, rawmax, rawmin, sp);
    statsred_fin_k<64, 1024><<<64, 256, 0, stream>>>(sp, g1, b1, scl[0], shf[0], 1.0 / 327680.0);
    pool_raw_k<8><<<512, 256, 0, stream>>>(rawmax, rawmin, scl[0], shf[0], xcat, 0);

    // layer 2: 64 -> 64 fused (BO=64)
    conv_fused_k<64, 64, 64, true><<<dim3(1, 1024), 256, 0, stream>>>(
        y1, wh2, scl[0], shf[0], y2, rawmax, rawmin, sp);
    statsred_fin_k<64, 1024><<<64, 256, 0, stream>>>(sp, g2, b2, scl[1], shf[1], 1.0 / 327680.0);
    pool_raw_k<8><<<512, 256, 0, stream>>>(rawmax, rawmin, scl[1], shf[1], xcat, 64);

    // layer 3: 64 -> 128 fused (BO=128)
    conv_fused_k<64, 128, 128, true><<<dim3(1, 1024), 256, 0, stream>>>(
        y2, wh3, scl[1], shf[1], y3, rawmax, rawmin, sp);
    statsred_fin_k<128, 1024><<<128, 256, 0, stream>>>(sp, g3, b3, scl[2], shf[2], 1.0 / 327680.0);
    pool_raw_k<16><<<1024, 256, 0, stream>>>(rawmax, rawmin, scl[2], shf[2], xcat, 128);

    // layer 4: 128 -> 256 fused (BO=128, 2 o-tiles)
    conv_fused_k<128, 256, 128, false><<<dim3(2, 1024), 256, 0, stream>>>(
        y3, wh4, scl[2], shf[2], nullptr, rawmax, rawmin, sp);
    statsred_fin_k<128, 1024><<<256, 256, 0, stream>>>(sp, g4, b4, scl[3], shf[3], 1.0 / 327680.0);
    pool_raw_k<32><<<2048, 256, 0, stream>>>(rawmax, rawmin, scl[3], shf[3], xcat, 256);

    // layer 5: 512 -> 512, single-bf16 weights, o-tile 128, stats fused
    conv5_mfma_k<512, 512><<<dim3(4, 128), 256, 0, stream>>>(xcat, wh5, y5, sp);
    statsred_fin_k<128, 128><<<512, 256, 0, stream>>>(sp, g5, b5, scl[4], shf[4], 1.0 / 16384.0);
    out_k<<<dim3(32, 8, 8), 256, 0, stream>>>(y5, scl[4], shf[4], (float*)d_out);
}